// Round 1
// 405.211 us; speedup vs baseline: 1.0409x; 1.0409x over previous
//
#include <hip/hip_runtime.h>
#include <cstdint>

// B=8, S=2048, D=1024 single-head attention with QKV projection.
// R7: 8-phase 256x256 GEMM template (T2+T3+T4+T5, m201 lineage) replacing the
// 2-barrier 128x256 core. 512 thr = 8 waves (2Mx4N), per-wave 128x64 out,
// mfma 16x16x32 bf16. BK=64, LDS 128 KiB = 2 dbuf x 4 regions x 16 KiB
// (A grouped by m-half, B grouped by n-half -> each phase's quadrant reads are
// disjoint from the region being staged). Counted vmcnt(4) once per K-tile,
// never drained to 0 in the loop; 2 half-tiles always in flight. XOR chunk
// swizzle on LDS (pre-swizzled global src + swizzled read). V-transpose is its
// own 256-thr kernel. Pipeline: prep -> QKV gemm(bias) -> memset(l) -> vtrans
// -> score gemm(exp+rowsum) -> PV gemm(1/l).

#define Bb 8
#define Ss 2048
#define Dd 1024

typedef unsigned short ushort_t;
typedef __attribute__((ext_vector_type(8))) short short8;
typedef __attribute__((ext_vector_type(4))) float floatx4;

__device__ inline ushort_t f2bf(float f) {
    unsigned int u = __float_as_uint(f);
    unsigned int r = (u + 0x7fffu + ((u >> 16) & 1u)) >> 16;
    return (ushort_t)r;
}
__device__ inline float bf2f(ushort_t u) {
    return __uint_as_float(((unsigned int)u) << 16);
}

__device__ inline floatx4 mfma16(short8 a, short8 b, floatx4 c) {
    return __builtin_amdgcn_mfma_f32_16x16x32_bf16(a, b, c, 0, 0, 0);
}

__device__ inline void gload16(const void* g, void* l) {
    __builtin_amdgcn_global_load_lds(
        (const __attribute__((address_space(1))) void*)g,
        (__attribute__((address_space(3))) void*)l, 16, 0, 0);
}

// ---------------------------------------------------------------------------
// 8-phase 256x256 NT GEMM core. A: M x K rows, B: N x K rows (both bf16,
// row-major, ld in elems). LDS regions (8192 elems = 16 KiB each):
//   0 = A m-half0 (rows r with (r>>6)&1==0), 1 = A m-half1,
//   2 = B n-half0 (rows with (r>>5)&1==0),   3 = B n-half1.
// Region row j: A: r = (j>>6)*128 + g*64 + (j&63); B: r = (j>>5)*64 + nh*32
// + (j&31). Row = 64 elems (128 B); 16B k-chunk q of row j stored at phys
// slot q^(j&7) (staged via pre-swizzled global source).
// Quadrant order (mh,nh): (0,0),(1,0),(0,1),(1,1) =>
//   region 2 dead after phase 2, region 0 after 3, regions 1,3 after 4.
// Stage schedule, body(t): ph1: A-mh1(t+1)->nbuf, ph2: B-nh1(t+1)->nbuf,
//   ph3: B-nh0(t+2)->curbuf, ph4: A-mh0(t+2)->curbuf, then vmcnt(4)+barrier
//   (drains everything except ph3/ph4 => tile t+1 fully resident).
// ---------------------------------------------------------------------------
__device__ __attribute__((always_inline)) void gemm_core256(
    const ushort_t* __restrict__ A, const ushort_t* __restrict__ B,
    int K, int lda, int ldb, int m0, int n0, int tid,
    ushort_t* lds, floatx4 acc[8][4])
{
    const int lane = tid & 63;
    const int wave = tid >> 6;
    const int l3   = lane >> 3;               // row within 8-row chunk
    const int kc   = ((lane & 7) ^ l3) * 8;   // pre-swizzled global k-chunk

    // staging source pointers: chunk c = wave + i*8 covers region rows c*8..+7
    const ushort_t* aS[2][2];
    const ushort_t* bS[2][2];
#pragma unroll
    for (int i = 0; i < 2; i++) {
#pragma unroll
        for (int g = 0; g < 2; g++) {
            const int r = i * 128 + g * 64 + wave * 8 + l3;
            aS[g][i] = A + (size_t)(m0 + r) * lda + kc;
        }
#pragma unroll
        for (int nh = 0; nh < 2; nh++) {
            const int c = wave + i * 8;
            const int r = (c >> 2) * 64 + nh * 32 + (c & 3) * 8 + l3;
            bS[nh][i] = B + (size_t)(n0 + r) * ldb + kc;
        }
    }

    // fragment-read bases (A row = lane&15, k = (lane>>4)*8 within k-step)
    const int jA   = (wave >> 2) * 64 + (lane & 15);
    const int jB   = (wave & 3) * 32 + (lane & 15);
    const int swz0 = (((lane >> 4) + 0) ^ (lane & 7)) * 8;
    const int swz1 = (((lane >> 4) + 4) ^ (lane & 7)) * 8;

#define STG(DST, REGI, SRC, KOFS)                                             \
    do {                                                                      \
        gload16(SRC[0] + (KOFS), (DST) + (REGI) * 8192 + wave * 512);         \
        gload16(SRC[1] + (KOFS), (DST) + (REGI) * 8192 + (wave + 8) * 512);   \
    } while (0)

#define PHASE(MH, NH, STGSTMT, VMSTMT)                                        \
    do {                                                                      \
        const ushort_t* ba  = cb + (MH) * 8192;                               \
        const ushort_t* bb2 = cb + (2 + (NH)) * 8192;                         \
        short8 af[4][2], bf[2][2];                                            \
        _Pragma("unroll")                                                     \
        for (int mi = 0; mi < 4; mi++) {                                      \
            af[mi][0] = *(const short8*)&ba[(jA + mi * 16) * 64 + swz0];      \
            af[mi][1] = *(const short8*)&ba[(jA + mi * 16) * 64 + swz1];      \
        }                                                                     \
        _Pragma("unroll")                                                     \
        for (int ni = 0; ni < 2; ni++) {                                      \
            bf[ni][0] = *(const short8*)&bb2[(jB + ni * 16) * 64 + swz0];     \
            bf[ni][1] = *(const short8*)&bb2[(jB + ni * 16) * 64 + swz1];     \
        }                                                                     \
        STGSTMT;                                                              \
        __builtin_amdgcn_sched_barrier(0);                                    \
        __builtin_amdgcn_s_barrier();                                         \
        asm volatile("s_waitcnt lgkmcnt(0)" ::: "memory");                    \
        __builtin_amdgcn_sched_barrier(0);                                    \
        __builtin_amdgcn_s_setprio(1);                                        \
        _Pragma("unroll")                                                     \
        for (int ks = 0; ks < 2; ks++)                                        \
            _Pragma("unroll")                                                 \
            for (int mi = 0; mi < 4; mi++)                                    \
                _Pragma("unroll")                                             \
                for (int ni = 0; ni < 2; ni++)                                \
                    acc[(MH) * 4 + mi][(NH) * 2 + ni] = mfma16(               \
                        af[mi][ks], bf[ni][ks],                               \
                        acc[(MH) * 4 + mi][(NH) * 2 + ni]);                   \
        __builtin_amdgcn_s_setprio(0);                                        \
        __builtin_amdgcn_sched_barrier(0);                                    \
        VMSTMT;                                                               \
        __builtin_amdgcn_s_barrier();                                         \
        __builtin_amdgcn_sched_barrier(0);                                    \
    } while (0)

    // prologue: tile 0 fully + tile 1 {B-nh0, A-mh0}; keep 4 loads in flight
    STG(lds, 0, aS[0], 0);
    STG(lds, 1, aS[1], 0);
    STG(lds, 2, bS[0], 0);
    STG(lds, 3, bS[1], 0);
    STG(lds + 32768, 2, bS[0], 64);
    STG(lds + 32768, 0, aS[0], 64);
    asm volatile("s_waitcnt vmcnt(4)" ::: "memory");
    __builtin_amdgcn_s_barrier();
    __builtin_amdgcn_sched_barrier(0);

    const int NT = K >> 6;
    for (int t = 0; t < NT; t++) {
        const ushort_t* cb = lds + (t & 1) * 32768;
        ushort_t* nb = lds + ((t + 1) & 1) * 32768;
        ushort_t* sb = lds + (t & 1) * 32768;
        const int k1 = (t + 1 < NT ? t + 1 : 0) << 6;   // wrap: dead writes
        const int k2 = (t + 2 < NT ? t + 2 : 0) << 6;
        PHASE(0, 0, STG(nb, 1, aS[1], k1), (void)0);
        PHASE(1, 0, STG(nb, 3, bS[1], k1), (void)0);
        PHASE(0, 1, STG(sb, 2, bS[0], k2), (void)0);
        PHASE(1, 1, STG(sb, 0, aS[0], k2),
              asm volatile("s_waitcnt vmcnt(4)" ::: "memory"));
    }
    // don't exit with gload_lds writes pending into (deallocatable) LDS
    asm volatile("s_waitcnt vmcnt(0)" ::: "memory");
#undef PHASE
#undef STG
}

// C/D layout 16x16 (m89/m91): col = lane&15, row = (lane>>4)*4 + reg
// EPI 0: bf16 out + aux[col] bias (QKV).
// EPI 1: bf16 out = exp(acc/32), rowsum atomics into aux (score).
// EPI 3: fp32 out * 1/aux[z*Ss+row] (PV).
template <int EPI>
__global__ __launch_bounds__(512, 2) void gemm256(
    const ushort_t* __restrict__ A, const ushort_t* __restrict__ B,
    void* __restrict__ Cv, float* __restrict__ aux,
    int K, int lda, int ldb, int ldc,
    size_t strideA, size_t strideB, size_t strideC)
{
    const int z = blockIdx.z;
    A += (size_t)z * strideA;
    B += (size_t)z * strideB;
    const int m0 = blockIdx.y * 256;
    const int n0 = blockIdx.x * 256;

    __shared__ __align__(16) ushort_t lds[2 * 4 * 8192];   // 128 KiB

    floatx4 acc[8][4] = {};
    gemm_core256(A, B, K, lda, ldb, m0, n0, (int)threadIdx.x, lds, acc);

    const int lane = threadIdx.x & 63;
    const int wave = threadIdx.x >> 6;
    const int row0 = m0 + (wave >> 2) * 128 + (lane >> 4) * 4;
    const int col0 = n0 + (wave & 3) * 64 + (lane & 15);

    if (EPI == 0) {
        ushort_t* Cb = (ushort_t*)Cv;
        float bval[4];
#pragma unroll
        for (int nf = 0; nf < 4; nf++) bval[nf] = aux[col0 + nf * 16];
#pragma unroll
        for (int mf = 0; mf < 8; mf++)
#pragma unroll
            for (int i = 0; i < 4; i++) {
                const size_t ro = (size_t)(row0 + mf * 16 + i) * ldc;
#pragma unroll
                for (int nf = 0; nf < 4; nf++)
                    Cb[ro + col0 + nf * 16] = f2bf(acc[mf][nf][i] + bval[nf]);
            }
    } else if (EPI == 1) {
        ushort_t* Cb = (ushort_t*)Cv + (size_t)z * strideC;
        float* ls = aux + z * Ss;
        float rs[8][4];
#pragma unroll
        for (int mf = 0; mf < 8; mf++)
#pragma unroll
            for (int i = 0; i < 4; i++) rs[mf][i] = 0.f;
#pragma unroll
        for (int mf = 0; mf < 8; mf++)
#pragma unroll
            for (int i = 0; i < 4; i++) {
                const size_t ro = (size_t)(row0 + mf * 16 + i) * ldc;
#pragma unroll
                for (int nf = 0; nf < 4; nf++) {
                    const ushort_t o = f2bf(__expf(acc[mf][nf][i] * 0.03125f));
                    Cb[ro + col0 + nf * 16] = o;
                    rs[mf][i] += bf2f(o);
                }
            }
#pragma unroll
        for (int mf = 0; mf < 8; mf++)
#pragma unroll
            for (int i = 0; i < 4; i++) {
                float s = rs[mf][i];
                s += __shfl_xor(s, 1);
                s += __shfl_xor(s, 2);
                s += __shfl_xor(s, 4);
                s += __shfl_xor(s, 8);
                rs[mf][i] = s;
            }
        if ((lane & 15) == 0) {
#pragma unroll
            for (int mf = 0; mf < 8; mf++)
#pragma unroll
                for (int i = 0; i < 4; i++)
                    atomicAdd(&ls[row0 + mf * 16 + i], rs[mf][i]);
        }
    } else {
        float* Cf = (float*)Cv + (size_t)z * strideC;
#pragma unroll
        for (int mf = 0; mf < 8; mf++)
#pragma unroll
            for (int i = 0; i < 4; i++) {
                const int gr = row0 + mf * 16 + i;
                const float iv = 1.0f / aux[z * Ss + gr];
#pragma unroll
                for (int nf = 0; nf < 4; nf++)
                    Cf[(size_t)gr * ldc + col0 + nf * 16] = acc[mf][nf][i] * iv;
            }
    }
}

// ---------------------------------------------------------------------------
// V-slice transpose: QKVb[z][s][2048+d] -> Vt[z][d][s], 64x64 bf16 tiles.
// ---------------------------------------------------------------------------
__global__ __launch_bounds__(256) void vtrans(
    const ushort_t* __restrict__ QKVb, ushort_t* __restrict__ Vt)
{
    __shared__ __align__(16) ushort_t tile[64][72];
    const int t = blockIdx.x;
    const int z = t >> 9, rem = t & 511;
    const int d0 = (rem & 15) * 64, s0 = (rem >> 4) * 64;
    const int tid = threadIdx.x;
    const int rr = tid >> 3;          // 0..31
    const int c8 = (tid & 7) * 8;     // 0..56
#pragma unroll
    for (int i = 0; i < 2; i++) {
        const int s = s0 + rr + i * 32;
        uint4 v = *(const uint4*)&QKVb[((size_t)(z * Ss + s)) * 3072 + 2048 + d0 + c8];
        *(uint4*)&tile[rr + i * 32][c8] = v;
    }
    __syncthreads();
#pragma unroll
    for (int i = 0; i < 2; i++) {
        const int d = rr + i * 32;
        ushort_t u[8];
#pragma unroll
        for (int j = 0; j < 8; j++) u[j] = tile[c8 + j][d];
        *(uint4*)&Vt[(size_t)z * Dd * Ss + (size_t)(d0 + d) * Ss + s0 + c8] =
            *(const uint4*)u;
    }
}

// ---------------------------------------------------------------------------
// prep: blocks [0,8192): x fp32->bf16; [8192,8960): W^T cvt; 8960: bias concat
// ---------------------------------------------------------------------------
__global__ __launch_bounds__(256) void prep(
    const float* __restrict__ x,
    const float* __restrict__ W0, const float* __restrict__ W1,
    const float* __restrict__ W2,
    const float* __restrict__ bq, const float* __restrict__ bk,
    const float* __restrict__ bv,
    ushort_t* __restrict__ xb, ushort_t* __restrict__ Wall,
    float* __restrict__ ball)
{
    const int bid = blockIdx.x;
    const int tid = threadIdx.x;

    if (bid < 8192) {
        const size_t i = (size_t)bid * 256 + tid;
        const float4* p = (const float4*)x + i * 2;
        float4 a = p[0], b = p[1];
        ushort_t u[8];
        u[0]=f2bf(a.x); u[1]=f2bf(a.y); u[2]=f2bf(a.z); u[3]=f2bf(a.w);
        u[4]=f2bf(b.x); u[5]=f2bf(b.y); u[6]=f2bf(b.z); u[7]=f2bf(b.w);
        *(uint4*)(xb + i * 8) = *(const uint4*)u;
    } else if (bid < 8960) {
        const int t = bid - 8192;
        const int z = t >> 8;
        const float* W = (z == 0) ? W0 : (z == 1) ? W1 : W2;
        ushort_t* Wt = Wall + (size_t)z * Dd * Dd;
        __shared__ float tt[64][65];
        const int n0 = ((t >> 4) & 15) * 64, k0 = (t & 15) * 64;
        const int r  = tid >> 4;
        const int c4 = (tid & 15) * 4;
#pragma unroll
        for (int i = 0; i < 4; i++) {
            float4 v = *(const float4*)&W[(size_t)(k0 + r + i * 16) * Dd + n0 + c4];
            tt[r + i * 16][c4 + 0] = v.x;
            tt[r + i * 16][c4 + 1] = v.y;
            tt[r + i * 16][c4 + 2] = v.z;
            tt[r + i * 16][c4 + 3] = v.w;
        }
        __syncthreads();
#pragma unroll
        for (int i = 0; i < 4; i++) {
            const int rn = r + i * 16;
            ushort_t u[4];
#pragma unroll
            for (int j = 0; j < 4; j++) u[j] = f2bf(tt[c4 + j][rn]);
            *(uint2*)&Wt[(size_t)(n0 + rn) * Dd + k0 + c4] = *(const uint2*)u;
        }
    } else {
#pragma unroll
        for (int j = 0; j < 12; j++) {
            const int idx = j * 256 + tid;
            float v = (idx < 1024) ? bq[idx]
                    : (idx < 2048) ? bk[idx - 1024] : bv[idx - 2048];
            ball[idx] = v;
        }
    }
}

// ---------------------------------------------------------------------------
extern "C" void kernel_launch(void* const* d_in, const int* in_sizes, int n_in,
                              void* d_out, int out_size, void* d_ws, size_t ws_size,
                              hipStream_t stream)
{
    const float* x  = (const float*)d_in[0];
    const float* Wq = (const float*)d_in[1];
    const float* bq = (const float*)d_in[2];
    const float* Wk = (const float*)d_in[3];
    const float* bk = (const float*)d_in[4];
    const float* Wv = (const float*)d_in[5];
    const float* bv = (const float*)d_in[6];
    float* out = (float*)d_out;

    char* ws = (char*)d_ws;
    const size_t MB = 1u << 20;
    // ws: [0,32) xb (dead after QKV) / Vt; [32,128) QKVb[16384][3072] bf16;
    //     [128,192) Pb = expP bf16; [192,+64K) lsum fp32[16384]
    // d_out doubles as prep scratch (read only before any out write):
    //     Wall bf16[3072][1024] @ +0, ball fp32[3072] @ +6MB
    ushort_t* xb   = (ushort_t*)(ws);
    ushort_t* Vt   = (ushort_t*)(ws);
    ushort_t* QKVb = (ushort_t*)(ws + 32 * MB);
    ushort_t* Pb   = (ushort_t*)(ws + 128 * MB);
    float*    lsum = (float*)(ws + 192 * MB);
    ushort_t* Wall = (ushort_t*)d_out;
    float*    ball = (float*)((char*)d_out + 6 * MB);

    // 0) prep
    prep<<<8961, 256, 0, stream>>>(x, Wq, Wk, Wv, bq, bk, bv, xb, Wall, ball);

    // 1) fused QKV projection: M=16384, N=3072, K=1024
    dim3 g1(3072 / 256, 16384 / 256, 1);
    gemm256<0><<<g1, 512, 0, stream>>>(xb, Wall, QKVb, ball,
                                       Dd, Dd, Dd, 3072, 0, 0, 0);

    // 2) zero row-sum accumulators; V transpose; scores(+exp,+rowsum)
    hipMemsetAsync(lsum, 0, (size_t)Bb * Ss * sizeof(float), stream);
    vtrans<<<4096, 256, 0, stream>>>(QKVb, Vt);
    dim3 g2(Ss / 256, Ss / 256, Bb);
    gemm256<1><<<g2, 512, 0, stream>>>(QKVb, QKVb + 1024, Pb, lsum,
                                       Dd, 3072, 3072, Ss,
                                       (size_t)Ss * 3072, (size_t)Ss * 3072,
                                       (size_t)Ss * Ss);

    // 3) out = (expP @ Vt^T) * 1/l : per-batch 2048x1024, K=2048, fp32 out
    dim3 g3(Dd / 256, Ss / 256, Bb);
    gemm256<3><<<g3, 512, 0, stream>>>(Pb, Vt, out, lsum,
                                       Ss, Ss, Ss, Dd,
                                       (size_t)Ss * Ss, (size_t)Dd * Ss,
                                       (size_t)Ss * Dd);
}

// Round 2
// 398.227 us; speedup vs baseline: 1.0591x; 1.0175x over previous
//
#include <hip/hip_runtime.h>
#include <cstdint>

// B=8, S=2048, D=1024 single-head attention with QKV projection.
// R8: R7's 8-phase 256x256 core + SNAKE quadrant order with fragment reuse
// (m201's "4 or 8 ds_reads/phase"). Quad order (0,0),(1,0),(1,1),(0,1):
// consecutive phases share A-half or B-half, so per-phase ds_reads drop from
// 12 to 12/8/4/8 (48 -> 32 per K64 tile, -33% LDS traffic). Frags aF[4][2]
// bF[2][2] persist across phases. Staging ledger re-derived for new region
// deaths: ph1->B1(t+1), ph2->A0(t+1) (nbuf); ph3->B0(t+2), ph4->A1(t+2)
// (curbuf); vmcnt(4) at ph4 drains exactly tile t+1. Everything else (16x16x32
// MFMA, XOR chunk swizzle = 0 bank conflicts, barriers/setprio, epilogues,
// vtrans, prep) unchanged from R7.

#define Bb 8
#define Ss 2048
#define Dd 1024

typedef unsigned short ushort_t;
typedef __attribute__((ext_vector_type(8))) short short8;
typedef __attribute__((ext_vector_type(4))) float floatx4;

__device__ inline ushort_t f2bf(float f) {
    unsigned int u = __float_as_uint(f);
    unsigned int r = (u + 0x7fffu + ((u >> 16) & 1u)) >> 16;
    return (ushort_t)r;
}
__device__ inline float bf2f(ushort_t u) {
    return __uint_as_float(((unsigned int)u) << 16);
}

__device__ inline floatx4 mfma16(short8 a, short8 b, floatx4 c) {
    return __builtin_amdgcn_mfma_f32_16x16x32_bf16(a, b, c, 0, 0, 0);
}

__device__ inline void gload16(const void* g, void* l) {
    __builtin_amdgcn_global_load_lds(
        (const __attribute__((address_space(1))) void*)g,
        (__attribute__((address_space(3))) void*)l, 16, 0, 0);
}

// ---------------------------------------------------------------------------
// 8-phase 256x256 NT GEMM core, snake order + frag reuse.
// LDS regions (8192 elems = 16 KiB each): 0 = A m-half0, 1 = A m-half1,
// 2 = B n-half0, 3 = B n-half1 (region row maps as in R7). Row = 64 elems;
// 16B k-chunk q of row j at phys slot q^(j&7) (pre-swizzled global source).
// Snake phases (qm,qn): ph1 (0,0) reads A0+B0; ph2 (1,0) reads A1, reuses B0;
// ph3 (1,1) reads B1, reuses A1; ph4 (0,1) reads A0, reuses B1.
// Region last-read: B0@ph1, A1@ph2, B1@ph3, A0@ph4.
// Stage: ph1: B1(t+1)->nb, ph2: A0(t+1)->nb, ph3: B0(t+2)->cb, ph4:
// A1(t+2)->cb + vmcnt(4) (drains exactly all four regions of tile t+1).
// ---------------------------------------------------------------------------
__device__ __attribute__((always_inline)) void gemm_core256(
    const ushort_t* __restrict__ A, const ushort_t* __restrict__ B,
    int K, int lda, int ldb, int m0, int n0, int tid,
    ushort_t* lds, floatx4 acc[8][4])
{
    const int lane = tid & 63;
    const int wave = tid >> 6;
    const int l3   = lane >> 3;               // row within 8-row chunk
    const int kc   = ((lane & 7) ^ l3) * 8;   // pre-swizzled global k-chunk

    // staging source pointers: chunk c = wave + i*8 covers region rows c*8..+7
    const ushort_t* aS[2][2];
    const ushort_t* bS[2][2];
#pragma unroll
    for (int i = 0; i < 2; i++) {
#pragma unroll
        for (int g = 0; g < 2; g++) {
            const int r = i * 128 + g * 64 + wave * 8 + l3;
            aS[g][i] = A + (size_t)(m0 + r) * lda + kc;
        }
#pragma unroll
        for (int nh = 0; nh < 2; nh++) {
            const int c = wave + i * 8;
            const int r = (c >> 2) * 64 + nh * 32 + (c & 3) * 8 + l3;
            bS[nh][i] = B + (size_t)(n0 + r) * ldb + kc;
        }
    }

    // fragment-read bases (row = lane&15, k-chunk = lane>>4 within k32-step)
    const int jA   = (wave >> 2) * 64 + (lane & 15);
    const int jB   = (wave & 3) * 32 + (lane & 15);
    const int swz0 = (((lane >> 4) + 0) ^ (lane & 7)) * 8;
    const int swz1 = (((lane >> 4) + 4) ^ (lane & 7)) * 8;

    short8 aF[4][2], bF[2][2];

#define STG(DST, REGI, SRC, KOFS)                                             \
    do {                                                                      \
        gload16(SRC[0] + (KOFS), (DST) + (REGI) * 8192 + wave * 512);         \
        gload16(SRC[1] + (KOFS), (DST) + (REGI) * 8192 + (wave + 8) * 512);   \
    } while (0)

#define RD_A(QM)                                                              \
    _Pragma("unroll")                                                         \
    for (int mi = 0; mi < 4; mi++) {                                          \
        const ushort_t* pA_ = cb + (QM) * 8192 + (jA + mi * 16) * 64;         \
        aF[mi][0] = *(const short8*)&pA_[swz0];                               \
        aF[mi][1] = *(const short8*)&pA_[swz1];                               \
    }

#define RD_B(QN)                                                              \
    _Pragma("unroll")                                                         \
    for (int ni = 0; ni < 2; ni++) {                                          \
        const ushort_t* pB_ = cb + (2 + (QN)) * 8192 + (jB + ni * 16) * 64;   \
        bF[ni][0] = *(const short8*)&pB_[swz0];                               \
        bF[ni][1] = *(const short8*)&pB_[swz1];                               \
    }

#define MM(QM, QN)                                                            \
    _Pragma("unroll")                                                         \
    for (int ks = 0; ks < 2; ks++)                                            \
        _Pragma("unroll")                                                     \
        for (int mi = 0; mi < 4; mi++)                                        \
            _Pragma("unroll")                                                 \
            for (int ni = 0; ni < 2; ni++)                                    \
                acc[(QM) * 4 + mi][(QN) * 2 + ni] =                           \
                    mfma16(aF[mi][ks], bF[ni][ks],                            \
                           acc[(QM) * 4 + mi][(QN) * 2 + ni]);

#define PHASE(RDS, MMS, STGS, VMS)                                            \
    do {                                                                      \
        RDS                                                                   \
        STGS;                                                                 \
        __builtin_amdgcn_sched_barrier(0);                                    \
        __builtin_amdgcn_s_barrier();                                         \
        asm volatile("s_waitcnt lgkmcnt(0)" ::: "memory");                    \
        __builtin_amdgcn_sched_barrier(0);                                    \
        __builtin_amdgcn_s_setprio(1);                                        \
        MMS                                                                   \
        __builtin_amdgcn_s_setprio(0);                                        \
        __builtin_amdgcn_sched_barrier(0);                                    \
        VMS;                                                                  \
        __builtin_amdgcn_s_barrier();                                         \
        __builtin_amdgcn_sched_barrier(0);                                    \
    } while (0)

    // prologue: tile 0 all four regions + tile 1 {B0, A1}; drain tile 0 only
    STG(lds, 0, aS[0], 0);
    STG(lds, 1, aS[1], 0);
    STG(lds, 2, bS[0], 0);
    STG(lds, 3, bS[1], 0);
    STG(lds + 32768, 2, bS[0], 64);
    STG(lds + 32768, 1, aS[1], 64);
    asm volatile("s_waitcnt vmcnt(4)" ::: "memory");
    __builtin_amdgcn_s_barrier();
    __builtin_amdgcn_sched_barrier(0);

    const int NT = K >> 6;
    for (int t = 0; t < NT; t++) {
        const ushort_t* cb = lds + (t & 1) * 32768;
        ushort_t* nb = lds + ((t + 1) & 1) * 32768;
        ushort_t* sb = lds + (t & 1) * 32768;
        const int k1 = (t + 1 < NT ? t + 1 : 0) << 6;   // wrap: dead writes
        const int k2 = (t + 2 < NT ? t + 2 : 0) << 6;
        PHASE(RD_A(0) RD_B(0), MM(0, 0), STG(nb, 3, bS[1], k1), (void)0);
        PHASE(RD_A(1),         MM(1, 0), STG(nb, 0, aS[0], k1), (void)0);
        PHASE(RD_B(1),         MM(1, 1), STG(sb, 2, bS[0], k2), (void)0);
        PHASE(RD_A(0),         MM(0, 1), STG(sb, 1, aS[1], k2),
              asm volatile("s_waitcnt vmcnt(4)" ::: "memory"));
    }
    // don't exit with gload_lds writes pending into (deallocatable) LDS
    asm volatile("s_waitcnt vmcnt(0)" ::: "memory");
#undef PHASE
#undef MM
#undef RD_B
#undef RD_A
#undef STG
}

// C/D layout 16x16 (m89/m91): col = lane&15, row = (lane>>4)*4 + reg
// EPI 0: bf16 out + aux[col] bias (QKV).
// EPI 1: bf16 out = exp(acc/32), rowsum atomics into aux (score).
// EPI 3: fp32 out * 1/aux[z*Ss+row] (PV).
template <int EPI>
__global__ __launch_bounds__(512, 2) void gemm256(
    const ushort_t* __restrict__ A, const ushort_t* __restrict__ B,
    void* __restrict__ Cv, float* __restrict__ aux,
    int K, int lda, int ldb, int ldc,
    size_t strideA, size_t strideB, size_t strideC)
{
    const int z = blockIdx.z;
    A += (size_t)z * strideA;
    B += (size_t)z * strideB;
    const int m0 = blockIdx.y * 256;
    const int n0 = blockIdx.x * 256;

    __shared__ __align__(16) ushort_t lds[2 * 4 * 8192];   // 128 KiB

    floatx4 acc[8][4] = {};
    gemm_core256(A, B, K, lda, ldb, m0, n0, (int)threadIdx.x, lds, acc);

    const int lane = threadIdx.x & 63;
    const int wave = threadIdx.x >> 6;
    const int row0 = m0 + (wave >> 2) * 128 + (lane >> 4) * 4;
    const int col0 = n0 + (wave & 3) * 64 + (lane & 15);

    if (EPI == 0) {
        ushort_t* Cb = (ushort_t*)Cv;
        float bval[4];
#pragma unroll
        for (int nf = 0; nf < 4; nf++) bval[nf] = aux[col0 + nf * 16];
#pragma unroll
        for (int mf = 0; mf < 8; mf++)
#pragma unroll
            for (int i = 0; i < 4; i++) {
                const size_t ro = (size_t)(row0 + mf * 16 + i) * ldc;
#pragma unroll
                for (int nf = 0; nf < 4; nf++)
                    Cb[ro + col0 + nf * 16] = f2bf(acc[mf][nf][i] + bval[nf]);
            }
    } else if (EPI == 1) {
        ushort_t* Cb = (ushort_t*)Cv + (size_t)z * strideC;
        float* ls = aux + z * Ss;
        float rs[8][4];
#pragma unroll
        for (int mf = 0; mf < 8; mf++)
#pragma unroll
            for (int i = 0; i < 4; i++) rs[mf][i] = 0.f;
#pragma unroll
        for (int mf = 0; mf < 8; mf++)
#pragma unroll
            for (int i = 0; i < 4; i++) {
                const size_t ro = (size_t)(row0 + mf * 16 + i) * ldc;
#pragma unroll
                for (int nf = 0; nf < 4; nf++) {
                    const ushort_t o = f2bf(__expf(acc[mf][nf][i] * 0.03125f));
                    Cb[ro + col0 + nf * 16] = o;
                    rs[mf][i] += bf2f(o);
                }
            }
#pragma unroll
        for (int mf = 0; mf < 8; mf++)
#pragma unroll
            for (int i = 0; i < 4; i++) {
                float s = rs[mf][i];
                s += __shfl_xor(s, 1);
                s += __shfl_xor(s, 2);
                s += __shfl_xor(s, 4);
                s += __shfl_xor(s, 8);
                rs[mf][i] = s;
            }
        if ((lane & 15) == 0) {
#pragma unroll
            for (int mf = 0; mf < 8; mf++)
#pragma unroll
                for (int i = 0; i < 4; i++)
                    atomicAdd(&ls[row0 + mf * 16 + i], rs[mf][i]);
        }
    } else {
        float* Cf = (float*)Cv + (size_t)z * strideC;
#pragma unroll
        for (int mf = 0; mf < 8; mf++)
#pragma unroll
            for (int i = 0; i < 4; i++) {
                const int gr = row0 + mf * 16 + i;
                const float iv = 1.0f / aux[z * Ss + gr];
#pragma unroll
                for (int nf = 0; nf < 4; nf++)
                    Cf[(size_t)gr * ldc + col0 + nf * 16] = acc[mf][nf][i] * iv;
            }
    }
}

// ---------------------------------------------------------------------------
// V-slice transpose: QKVb[z][s][2048+d] -> Vt[z][d][s], 64x64 bf16 tiles.
// ---------------------------------------------------------------------------
__global__ __launch_bounds__(256) void vtrans(
    const ushort_t* __restrict__ QKVb, ushort_t* __restrict__ Vt)
{
    __shared__ __align__(16) ushort_t tile[64][72];
    const int t = blockIdx.x;
    const int z = t >> 9, rem = t & 511;
    const int d0 = (rem & 15) * 64, s0 = (rem >> 4) * 64;
    const int tid = threadIdx.x;
    const int rr = tid >> 3;          // 0..31
    const int c8 = (tid & 7) * 8;     // 0..56
#pragma unroll
    for (int i = 0; i < 2; i++) {
        const int s = s0 + rr + i * 32;
        uint4 v = *(const uint4*)&QKVb[((size_t)(z * Ss + s)) * 3072 + 2048 + d0 + c8];
        *(uint4*)&tile[rr + i * 32][c8] = v;
    }
    __syncthreads();
#pragma unroll
    for (int i = 0; i < 2; i++) {
        const int d = rr + i * 32;
        ushort_t u[8];
#pragma unroll
        for (int j = 0; j < 8; j++) u[j] = tile[c8 + j][d];
        *(uint4*)&Vt[(size_t)z * Dd * Ss + (size_t)(d0 + d) * Ss + s0 + c8] =
            *(const uint4*)u;
    }
}

// ---------------------------------------------------------------------------
// prep: blocks [0,8192): x fp32->bf16; [8192,8960): W^T cvt; 8960: bias concat
// ---------------------------------------------------------------------------
__global__ __launch_bounds__(256) void prep(
    const float* __restrict__ x,
    const float* __restrict__ W0, const float* __restrict__ W1,
    const float* __restrict__ W2,
    const float* __restrict__ bq, const float* __restrict__ bk,
    const float* __restrict__ bv,
    ushort_t* __restrict__ xb, ushort_t* __restrict__ Wall,
    float* __restrict__ ball)
{
    const int bid = blockIdx.x;
    const int tid = threadIdx.x;

    if (bid < 8192) {
        const size_t i = (size_t)bid * 256 + tid;
        const float4* p = (const float4*)x + i * 2;
        float4 a = p[0], b = p[1];
        ushort_t u[8];
        u[0]=f2bf(a.x); u[1]=f2bf(a.y); u[2]=f2bf(a.z); u[3]=f2bf(a.w);
        u[4]=f2bf(b.x); u[5]=f2bf(b.y); u[6]=f2bf(b.z); u[7]=f2bf(b.w);
        *(uint4*)(xb + i * 8) = *(const uint4*)u;
    } else if (bid < 8960) {
        const int t = bid - 8192;
        const int z = t >> 8;
        const float* W = (z == 0) ? W0 : (z == 1) ? W1 : W2;
        ushort_t* Wt = Wall + (size_t)z * Dd * Dd;
        __shared__ float tt[64][65];
        const int n0 = ((t >> 4) & 15) * 64, k0 = (t & 15) * 64;
        const int r  = tid >> 4;
        const int c4 = (tid & 15) * 4;
#pragma unroll
        for (int i = 0; i < 4; i++) {
            float4 v = *(const float4*)&W[(size_t)(k0 + r + i * 16) * Dd + n0 + c4];
            tt[r + i * 16][c4 + 0] = v.x;
            tt[r + i * 16][c4 + 1] = v.y;
            tt[r + i * 16][c4 + 2] = v.z;
            tt[r + i * 16][c4 + 3] = v.w;
        }
        __syncthreads();
#pragma unroll
        for (int i = 0; i < 4; i++) {
            const int rn = r + i * 16;
            ushort_t u[4];
#pragma unroll
            for (int j = 0; j < 4; j++) u[j] = f2bf(tt[c4 + j][rn]);
            *(uint2*)&Wt[(size_t)(n0 + rn) * Dd + k0 + c4] = *(const uint2*)u;
        }
    } else {
#pragma unroll
        for (int j = 0; j < 12; j++) {
            const int idx = j * 256 + tid;
            float v = (idx < 1024) ? bq[idx]
                    : (idx < 2048) ? bk[idx - 1024] : bv[idx - 2048];
            ball[idx] = v;
        }
    }
}

// ---------------------------------------------------------------------------
extern "C" void kernel_launch(void* const* d_in, const int* in_sizes, int n_in,
                              void* d_out, int out_size, void* d_ws, size_t ws_size,
                              hipStream_t stream)
{
    const float* x  = (const float*)d_in[0];
    const float* Wq = (const float*)d_in[1];
    const float* bq = (const float*)d_in[2];
    const float* Wk = (const float*)d_in[3];
    const float* bk = (const float*)d_in[4];
    const float* Wv = (const float*)d_in[5];
    const float* bv = (const float*)d_in[6];
    float* out = (float*)d_out;

    char* ws = (char*)d_ws;
    const size_t MB = 1u << 20;
    // ws: [0,32) xb (dead after QKV) / Vt; [32,128) QKVb[16384][3072] bf16;
    //     [128,192) Pb = expP bf16; [192,+64K) lsum fp32[16384]
    // d_out doubles as prep scratch (read only before any out write):
    //     Wall bf16[3072][1024] @ +0, ball fp32[3072] @ +6MB
    ushort_t* xb   = (ushort_t*)(ws);
    ushort_t* Vt   = (ushort_t*)(ws);
    ushort_t* QKVb = (ushort_t*)(ws + 32 * MB);
    ushort_t* Pb   = (ushort_t*)(ws + 128 * MB);
    float*    lsum = (float*)(ws + 192 * MB);
    ushort_t* Wall = (ushort_t*)d_out;
    float*    ball = (float*)((char*)d_out + 6 * MB);

    // 0) prep
    prep<<<8961, 256, 0, stream>>>(x, Wq, Wk, Wv, bq, bk, bv, xb, Wall, ball);

    // 1) fused QKV projection: M=16384, N=3072, K=1024
    dim3 g1(3072 / 256, 16384 / 256, 1);
    gemm256<0><<<g1, 512, 0, stream>>>(xb, Wall, QKVb, ball,
                                       Dd, Dd, Dd, 3072, 0, 0, 0);

    // 2) zero row-sum accumulators; V transpose; scores(+exp,+rowsum)
    hipMemsetAsync(lsum, 0, (size_t)Bb * Ss * sizeof(float), stream);
    vtrans<<<4096, 256, 0, stream>>>(QKVb, Vt);
    dim3 g2(Ss / 256, Ss / 256, Bb);
    gemm256<1><<<g2, 512, 0, stream>>>(QKVb, QKVb + 1024, Pb, lsum,
                                       Dd, 3072, 3072, Ss,
                                       (size_t)Ss * 3072, (size_t)Ss * 3072,
                                       (size_t)Ss * Ss);

    // 3) out = (expP @ Vt^T) * 1/l : per-batch 2048x1024, K=2048, fp32 out
    dim3 g3(Dd / 256, Ss / 256, Bb);
    gemm256<3><<<g3, 512, 0, stream>>>(Pb, Vt, out, lsum,
                                       Ss, Ss, Ss, Dd,
                                       (size_t)Ss * Ss, (size_t)Dd * Ss,
                                       (size_t)Ss * Dd);
}

// Round 4
// 372.419 us; speedup vs baseline: 1.1325x; 1.0693x over previous
//
#include <hip/hip_runtime.h>
#include <cstdint>

// B=8, S=2048, D=1024 single-head attention with QKV projection.
// R9b: identical to R9 (container infra failure, no counters; ledgers
// re-audited — barriers uniform, vmcnt(4) drains exactly tile t+1, region
// read/stage pairs barrier-separated). 2-barrier-per-tile pipelined core:
// per K64-tile, header reads ALL B frags (8 b128, live in regs whole tile)
// + A quarter0; then 4 phases {lgkm0; 16 MFMA; read next A quarter (4 b128,
// ping-pong aE/aO); stage}. Reads for phase p+1 issue after phase p's MFMAs
// -> LDS overlaps MFMA drain. Reads/tile 24 (minimum). BAR1 after ph2
// (B-region header reads vs B(t+2) stages into cb), BAR2 after ph4's
// vmcnt(4) (publishes t+1 residency, protects A-region reuse).
// XOR chunk swizzle (0 bank conflicts). Epilogues/vtrans/prep unchanged.

#define Bb 8
#define Ss 2048
#define Dd 1024

typedef unsigned short ushort_t;
typedef __attribute__((ext_vector_type(8))) short short8;
typedef __attribute__((ext_vector_type(4))) float floatx4;

__device__ inline ushort_t f2bf(float f) {
    unsigned int u = __float_as_uint(f);
    unsigned int r = (u + 0x7fffu + ((u >> 16) & 1u)) >> 16;
    return (ushort_t)r;
}
__device__ inline float bf2f(ushort_t u) {
    return __uint_as_float(((unsigned int)u) << 16);
}

__device__ inline floatx4 mfma16(short8 a, short8 b, floatx4 c) {
    return __builtin_amdgcn_mfma_f32_16x16x32_bf16(a, b, c, 0, 0, 0);
}

__device__ inline void gload16(const void* g, void* l) {
    __builtin_amdgcn_global_load_lds(
        (const __attribute__((address_space(1))) void*)g,
        (__attribute__((address_space(3))) void*)l, 16, 0, 0);
}

// ---------------------------------------------------------------------------
// LDS regions (8192 elems = 16 KiB each): 0 = A {rows 0-63,128-191},
// 1 = A {64-127,192-255}, 2 = B cols {0-31,64-95,128-159,192-223},
// 3 = B cols {32-63,96-127,160-191,224-255}. Row = 64 elems (128 B); 16B
// k-chunk q of region row j at phys slot q^(j&7) (pre-swizzled global src).
// Per-wave output 128x64: A quarters q: region q>>1, row (wave>>2)*64 +
// (q&1)*32 + mi*16 + (lane&15); B frag nf: region 2+(nf>>1), row
// (wave&3)*32 + (nf&1)*16 + (lane&15).
// ---------------------------------------------------------------------------
__device__ __attribute__((always_inline)) void gemm_core256(
    const ushort_t* __restrict__ A, const ushort_t* __restrict__ B,
    int K, int lda, int ldb, int m0, int n0, int tid,
    ushort_t* lds, floatx4 acc[8][4])
{
    const int lane = tid & 63;
    const int wave = tid >> 6;
    const int l3   = lane >> 3;               // row within 8-row chunk
    const int kc   = ((lane & 7) ^ l3) * 8;   // pre-swizzled global k-chunk

    // staging source pointers: chunk c = wave + i*8 covers region rows c*8..+7
    const ushort_t* aS[2][2];
    const ushort_t* bS[2][2];
#pragma unroll
    for (int i = 0; i < 2; i++) {
#pragma unroll
        for (int g = 0; g < 2; g++) {
            const int r = i * 128 + g * 64 + wave * 8 + l3;
            aS[g][i] = A + (size_t)(m0 + r) * lda + kc;
        }
#pragma unroll
        for (int nh = 0; nh < 2; nh++) {
            const int c = wave + i * 8;
            const int r = (c >> 2) * 64 + nh * 32 + (c & 3) * 8 + l3;
            bS[nh][i] = B + (size_t)(n0 + r) * ldb + kc;
        }
    }

    const int jA   = (wave >> 2) * 64 + (lane & 15);
    const int jB   = (wave & 3) * 32 + (lane & 15);
    const int swz0 = (((lane >> 4) + 0) ^ (lane & 7)) * 8;
    const int swz1 = (((lane >> 4) + 4) ^ (lane & 7)) * 8;

    short8 bFr[4][2];            // all B frags, live across whole tile
    short8 aE[2][2], aO[2][2];   // A quarter ping-pong

#define STG(DST, REGI, SRC, KOFS)                                             \
    do {                                                                      \
        gload16(SRC[0] + (KOFS), (DST) + (REGI) * 8192 + wave * 512);         \
        gload16(SRC[1] + (KOFS), (DST) + (REGI) * 8192 + (wave + 8) * 512);   \
    } while (0)

#define RD_B_ALL(BUF)                                                         \
    _Pragma("unroll")                                                         \
    for (int nf = 0; nf < 4; nf++) {                                          \
        const ushort_t* pB_ =                                                 \
            (BUF) + (2 + (nf >> 1)) * 8192 + (jB + (nf & 1) * 16) * 64;       \
        bFr[nf][0] = *(const short8*)&pB_[swz0];                              \
        bFr[nf][1] = *(const short8*)&pB_[swz1];                              \
    }

#define RD_A(BUF, Q, DST)                                                     \
    _Pragma("unroll")                                                         \
    for (int mi = 0; mi < 2; mi++) {                                          \
        const ushort_t* pA_ = (BUF) + ((Q) >> 1) * 8192 +                     \
                              (jA + ((Q) & 1) * 32 + mi * 16) * 64;           \
        DST[mi][0] = *(const short8*)&pA_[swz0];                              \
        DST[mi][1] = *(const short8*)&pA_[swz1];                              \
    }

#define MM(Q, ASRC)                                                           \
    _Pragma("unroll")                                                         \
    for (int ks = 0; ks < 2; ks++)                                            \
        _Pragma("unroll")                                                     \
        for (int mi = 0; mi < 2; mi++)                                        \
            _Pragma("unroll")                                                 \
            for (int nf = 0; nf < 4; nf++)                                    \
                acc[(Q) * 2 + mi][nf] =                                       \
                    mfma16(ASRC[mi][ks], bFr[nf][ks], acc[(Q) * 2 + mi][nf]);

#define MMPH(Q, ASRC)                                                         \
    do {                                                                      \
        asm volatile("s_waitcnt lgkmcnt(0)" ::: "memory");                    \
        __builtin_amdgcn_sched_barrier(0);                                    \
        __builtin_amdgcn_s_setprio(1);                                        \
        MM(Q, ASRC);                                                          \
        __builtin_amdgcn_s_setprio(0);                                        \
        __builtin_amdgcn_sched_barrier(0);                                    \
    } while (0)

    // prologue: tile0 all regions + tile1 {B0,B1}; drain tile0 only
    STG(lds, 0, aS[0], 0);
    STG(lds, 1, aS[1], 0);
    STG(lds, 2, bS[0], 0);
    STG(lds, 3, bS[1], 0);
    STG(lds + 32768, 2, bS[0], 64);
    STG(lds + 32768, 3, bS[1], 64);
    asm volatile("s_waitcnt vmcnt(4)" ::: "memory");
    __builtin_amdgcn_s_barrier();
    __builtin_amdgcn_sched_barrier(0);

    const int NT = K >> 6;
    for (int t = 0; t < NT; t++) {
        const ushort_t* cb = lds + (t & 1) * 32768;
        ushort_t* nb = lds + ((t + 1) & 1) * 32768;
        ushort_t* sb = lds + (t & 1) * 32768;
        const int k1 = (t + 1 < NT ? t + 1 : 0) << 6;   // wrap: dead writes
        const int k2 = (t + 2 < NT ? t + 2 : 0) << 6;

        // tile header: B all + A quarter0
        RD_B_ALL(cb);
        RD_A(cb, 0, aE);

        // ph1
        MMPH(0, aE);
        RD_A(cb, 1, aO);
        STG(nb, 0, aS[0], k1);
        // ph2
        MMPH(1, aO);
        RD_A(cb, 2, aE);
        STG(nb, 1, aS[1], k1);
        __builtin_amdgcn_sched_barrier(0);
        __builtin_amdgcn_s_barrier();          // BAR1: B reads vs B(t+2) stage
        __builtin_amdgcn_sched_barrier(0);
        // ph3
        MMPH(2, aE);
        RD_A(cb, 3, aO);
        STG(sb, 2, bS[0], k2);
        // ph4
        MMPH(3, aO);
        STG(sb, 3, bS[1], k2);
        __builtin_amdgcn_sched_barrier(0);
        asm volatile("s_waitcnt vmcnt(4)" ::: "memory");
        __builtin_amdgcn_s_barrier();          // BAR2: tile t+1 resident
        __builtin_amdgcn_sched_barrier(0);
    }
    // don't exit with gload_lds writes pending into (deallocatable) LDS
    asm volatile("s_waitcnt vmcnt(0)" ::: "memory");
#undef MMPH
#undef MM
#undef RD_A
#undef RD_B_ALL
#undef STG
}

// C/D layout 16x16 (m89/m91): col = lane&15, row = (lane>>4)*4 + reg
// EPI 0: bf16 out + aux[col] bias (QKV).
// EPI 1: bf16 out = exp(acc/32), rowsum atomics into aux (score).
// EPI 3: fp32 out * 1/aux[z*Ss+row] (PV).
template <int EPI>
__global__ __launch_bounds__(512, 2) void gemm256(
    const ushort_t* __restrict__ A, const ushort_t* __restrict__ B,
    void* __restrict__ Cv, float* __restrict__ aux,
    int K, int lda, int ldb, int ldc,
    size_t strideA, size_t strideB, size_t strideC)
{
    const int z = blockIdx.z;
    A += (size_t)z * strideA;
    B += (size_t)z * strideB;
    const int m0 = blockIdx.y * 256;
    const int n0 = blockIdx.x * 256;

    __shared__ __align__(16) ushort_t lds[2 * 4 * 8192];   // 128 KiB

    floatx4 acc[8][4] = {};
    gemm_core256(A, B, K, lda, ldb, m0, n0, (int)threadIdx.x, lds, acc);

    const int lane = threadIdx.x & 63;
    const int wave = threadIdx.x >> 6;
    const int row0 = m0 + (wave >> 2) * 128 + (lane >> 4) * 4;
    const int col0 = n0 + (wave & 3) * 64 + (lane & 15);

    if (EPI == 0) {
        ushort_t* Cb = (ushort_t*)Cv;
        float bval[4];
#pragma unroll
        for (int nf = 0; nf < 4; nf++) bval[nf] = aux[col0 + nf * 16];
#pragma unroll
        for (int mf = 0; mf < 8; mf++)
#pragma unroll
            for (int i = 0; i < 4; i++) {
                const size_t ro = (size_t)(row0 + mf * 16 + i) * ldc;
#pragma unroll
                for (int nf = 0; nf < 4; nf++)
                    Cb[ro + col0 + nf * 16] = f2bf(acc[mf][nf][i] + bval[nf]);
            }
    } else if (EPI == 1) {
        ushort_t* Cb = (ushort_t*)Cv + (size_t)z * strideC;
        float* ls = aux + z * Ss;
        float rs[8][4];
#pragma unroll
        for (int mf = 0; mf < 8; mf++)
#pragma unroll
            for (int i = 0; i < 4; i++) rs[mf][i] = 0.f;
#pragma unroll
        for (int mf = 0; mf < 8; mf++)
#pragma unroll
            for (int i = 0; i < 4; i++) {
                const size_t ro = (size_t)(row0 + mf * 16 + i) * ldc;
#pragma unroll
                for (int nf = 0; nf < 4; nf++) {
                    const ushort_t o = f2bf(__expf(acc[mf][nf][i] * 0.03125f));
                    Cb[ro + col0 + nf * 16] = o;
                    rs[mf][i] += bf2f(o);
                }
            }
#pragma unroll
        for (int mf = 0; mf < 8; mf++)
#pragma unroll
            for (int i = 0; i < 4; i++) {
                float s = rs[mf][i];
                s += __shfl_xor(s, 1);
                s += __shfl_xor(s, 2);
                s += __shfl_xor(s, 4);
                s += __shfl_xor(s, 8);
                rs[mf][i] = s;
            }
        if ((lane & 15) == 0) {
#pragma unroll
            for (int mf = 0; mf < 8; mf++)
#pragma unroll
                for (int i = 0; i < 4; i++)
                    atomicAdd(&ls[row0 + mf * 16 + i], rs[mf][i]);
        }
    } else {
        float* Cf = (float*)Cv + (size_t)z * strideC;
#pragma unroll
        for (int mf = 0; mf < 8; mf++)
#pragma unroll
            for (int i = 0; i < 4; i++) {
                const int gr = row0 + mf * 16 + i;
                const float iv = 1.0f / aux[z * Ss + gr];
#pragma unroll
                for (int nf = 0; nf < 4; nf++)
                    Cf[(size_t)gr * ldc + col0 + nf * 16] = acc[mf][nf][i] * iv;
            }
    }
}

// ---------------------------------------------------------------------------
// V-slice transpose: QKVb[z][s][2048+d] -> Vt[z][d][s], 64x64 bf16 tiles.
// ---------------------------------------------------------------------------
__global__ __launch_bounds__(256) void vtrans(
    const ushort_t* __restrict__ QKVb, ushort_t* __restrict__ Vt)
{
    __shared__ __align__(16) ushort_t tile[64][72];
    const int t = blockIdx.x;
    const int z = t >> 9, rem = t & 511;
    const int d0 = (rem & 15) * 64, s0 = (rem >> 4) * 64;
    const int tid = threadIdx.x;
    const int rr = tid >> 3;          // 0..31
    const int c8 = (tid & 7) * 8;     // 0..56
#pragma unroll
    for (int i = 0; i < 2; i++) {
        const int s = s0 + rr + i * 32;
        uint4 v = *(const uint4*)&QKVb[((size_t)(z * Ss + s)) * 3072 + 2048 + d0 + c8];
        *(uint4*)&tile[rr + i * 32][c8] = v;
    }
    __syncthreads();
#pragma unroll
    for (int i = 0; i < 2; i++) {
        const int d = rr + i * 32;
        ushort_t u[8];
#pragma unroll
        for (int j = 0; j < 8; j++) u[j] = tile[c8 + j][d];
        *(uint4*)&Vt[(size_t)z * Dd * Ss + (size_t)(d0 + d) * Ss + s0 + c8] =
            *(const uint4*)u;
    }
}

// ---------------------------------------------------------------------------
// prep: blocks [0,8192): x fp32->bf16; [8192,8960): W^T cvt; 8960: bias concat
// ---------------------------------------------------------------------------
__global__ __launch_bounds__(256) void prep(
    const float* __restrict__ x,
    const float* __restrict__ W0, const float* __restrict__ W1,
    const float* __restrict__ W2,
    const float* __restrict__ bq, const float* __restrict__ bk,
    const float* __restrict__ bv,
    ushort_t* __restrict__ xb, ushort_t* __restrict__ Wall,
    float* __restrict__ ball)
{
    const int bid = blockIdx.x;
    const int tid = threadIdx.x;

    if (bid < 8192) {
        const size_t i = (size_t)bid * 256 + tid;
        const float4* p = (const float4*)x + i * 2;
        float4 a = p[0], b = p[1];
        ushort_t u[8];
        u[0]=f2bf(a.x); u[1]=f2bf(a.y); u[2]=f2bf(a.z); u[3]=f2bf(a.w);
        u[4]=f2bf(b.x); u[5]=f2bf(b.y); u[6]=f2bf(b.z); u[7]=f2bf(b.w);
        *(uint4*)(xb + i * 8) = *(const uint4*)u;
    } else if (bid < 8960) {
        const int t = bid - 8192;
        const int z = t >> 8;
        const float* W = (z == 0) ? W0 : (z == 1) ? W1 : W2;
        ushort_t* Wt = Wall + (size_t)z * Dd * Dd;
        __shared__ float tt[64][65];
        const int n0 = ((t >> 4) & 15) * 64, k0 = (t & 15) * 64;
        const int r  = tid >> 4;
        const int c4 = (tid & 15) * 4;
#pragma unroll
        for (int i = 0; i < 4; i++) {
            float4 v = *(const float4*)&W[(size_t)(k0 + r + i * 16) * Dd + n0 + c4];
            tt[r + i * 16][c4 + 0] = v.x;
            tt[r + i * 16][c4 + 1] = v.y;
            tt[r + i * 16][c4 + 2] = v.z;
            tt[r + i * 16][c4 + 3] = v.w;
        }
        __syncthreads();
#pragma unroll
        for (int i = 0; i < 4; i++) {
            const int rn = r + i * 16;
            ushort_t u[4];
#pragma unroll
            for (int j = 0; j < 4; j++) u[j] = f2bf(tt[c4 + j][rn]);
            *(uint2*)&Wt[(size_t)(n0 + rn) * Dd + k0 + c4] = *(const uint2*)u;
        }
    } else {
#pragma unroll
        for (int j = 0; j < 12; j++) {
            const int idx = j * 256 + tid;
            float v = (idx < 1024) ? bq[idx]
                    : (idx < 2048) ? bk[idx - 1024] : bv[idx - 2048];
            ball[idx] = v;
        }
    }
}

// ---------------------------------------------------------------------------
extern "C" void kernel_launch(void* const* d_in, const int* in_sizes, int n_in,
                              void* d_out, int out_size, void* d_ws, size_t ws_size,
                              hipStream_t stream)
{
    const float* x  = (const float*)d_in[0];
    const float* Wq = (const float*)d_in[1];
    const float* bq = (const float*)d_in[2];
    const float* Wk = (const float*)d_in[3];
    const float* bk = (const float*)d_in[4];
    const float* Wv = (const float*)d_in[5];
    const float* bv = (const float*)d_in[6];
    float* out = (float*)d_out;

    char* ws = (char*)d_ws;
    const size_t MB = 1u << 20;
    // ws: [0,32) xb (dead after QKV) / Vt; [32,128) QKVb[16384][3072] bf16;
    //     [128,192) Pb = expP bf16; [192,+64K) lsum fp32[16384]
    // d_out doubles as prep scratch (read only before any out write):
    //     Wall bf16[3072][1024] @ +0, ball fp32[3072] @ +6MB
    ushort_t* xb   = (ushort_t*)(ws);
    ushort_t* Vt   = (ushort_t*)(ws);
    ushort_t* QKVb = (ushort_t*)(ws + 32 * MB);
    ushort_t* Pb   = (ushort_t*)(ws + 128 * MB);
    float*    lsum = (float*)(ws + 192 * MB);
    ushort_t* Wall = (ushort_t*)d_out;
    float*    ball = (float*)((char*)d_out + 6 * MB);

    // 0) prep
    prep<<<8961, 256, 0, stream>>>(x, Wq, Wk, Wv, bq, bk, bv, xb, Wall, ball);

    // 1) fused QKV projection: M=16384, N=3072, K=1024
    dim3 g1(3072 / 256, 16384 / 256, 1);
    gemm256<0><<<g1, 512, 0, stream>>>(xb, Wall, QKVb, ball,
                                       Dd, Dd, Dd, 3072, 0, 0, 0);

    // 2) zero row-sum accumulators; V transpose; scores(+exp,+rowsum)
    hipMemsetAsync(lsum, 0, (size_t)Bb * Ss * sizeof(float), stream);
    vtrans<<<4096, 256, 0, stream>>>(QKVb, Vt);
    dim3 g2(Ss / 256, Ss / 256, Bb);
    gemm256<1><<<g2, 512, 0, stream>>>(QKVb, QKVb + 1024, Pb, lsum,
                                       Dd, 3072, 3072, Ss,
                                       (size_t)Ss * 3072, (size_t)Ss * 3072,
                                       (size_t)Ss * Ss);

    // 3) out = (expP @ Vt^T) * 1/l : per-batch 2048x1024, K=2048, fp32 out
    dim3 g3(Dd / 256, Ss / 256, Bb);
    gemm256<3><<<g3, 512, 0, stream>>>(Pb, Vt, out, lsum,
                                       Ss, Ss, Ss, Dd,
                                       (size_t)Ss * Ss, (size_t)Dd * Ss,
                                       (size_t)Ss * Dd);
}